// Round 1
// baseline (395.508 us; speedup 1.0000x reference)
//
#include <hip/hip_runtime.h>
#include <cstdint>

// CrossViewBlockTransformer on MI355X (gfx950).
// One wave (64 lanes) per 4x4 image block; WG = 64 threads (no barriers needed:
// all LDS buffers are wave-private). Matmuls via v_mfma_f32_16x16x16_bf16.
// q/k path computed in split precision (bf16 hi+lo) to keep softmax accurate;
// v/attn/O/fc single bf16; softmax/GroupNorm/residual in fp32.

typedef float  f4    __attribute__((ext_vector_type(4)));
typedef float  f32x4 __attribute__((ext_vector_type(4)));
typedef short  s16x4 __attribute__((ext_vector_type(4)));
typedef __bf16 bf16;

#define MFMA(a, b, c) __builtin_amdgcn_mfma_f32_16x16x16bf16_1k((a), (b), (c), 0, 0, 0)

__device__ __forceinline__ unsigned short bfbits(float x) {
  return __builtin_bit_cast(unsigned short, (bf16)x);
}
// fp32 -> (hi bf16 | lo bf16 << 16), hi+lo reconstructs x to ~2^-17 rel
__device__ __forceinline__ uint32_t packsplit(float x) {
  bf16 h = (bf16)x;
  bf16 l = (bf16)(x - (float)h);
  return (uint32_t)__builtin_bit_cast(unsigned short, h) |
         ((uint32_t)__builtin_bit_cast(unsigned short, l) << 16);
}
__device__ __forceinline__ float unsplit(uint32_t w) {
  return __builtin_bit_cast(float, w << 16) +
         __builtin_bit_cast(float, w & 0xffff0000u);
}

__global__ void __launch_bounds__(64, 2)
cvbt_kernel(const float* __restrict__ qx, const float* __restrict__ rx,
            const float* __restrict__ Wq, const float* __restrict__ Wk,
            const float* __restrict__ Wv, const float* __restrict__ Wfc,
            const float* __restrict__ gw, const float* __restrict__ gb,
            float* __restrict__ out)
{
  // ---- wave-private LDS ----
  // sXq/sXr: input blocks as (hi|lo) bf16 pairs, [c=64][n=16], stride 17 dwords
  __shared__ uint32_t sXq[64 * 17];                       // 4352 B
  __shared__ uint32_t sXr[64 * 17];                       // 4352 B
  // sQT/sKT: q^T / k^T, [n=16][p: hi 0..63 | lo 64..127 | pad], stride 132
  __shared__ __align__(16) unsigned short sQT[16 * 132];  // 4224 B
  __shared__ __align__(16) unsigned short sKT[16 * 132];  // 4224 B
  __shared__ __align__(16) unsigned short sV [64 * 20];   // v[p][m]   2560 B
  __shared__ __align__(16) unsigned short sP [16 * 20];   // attn[n][m] 640 B
  __shared__ __align__(16) unsigned short sO [64 * 20];   // O[p][n]   2560 B
  __shared__ float sGn[128];                              //  512 B  (21424 total)

  const int lane = threadIdx.x;
  const int n = lane & 15;   // col within 16-tile
  const int g = lane >> 4;   // 4-row group

  sGn[lane]      = gw[lane];
  sGn[64 + lane] = gb[lane];

  // ---- preload Wq, Wk as split (hi/lo) A-fragments: W[16mt + n][16kt + 4g + j]
  s16x4 wqh[4][4], wql[4][4], wkh[4][4], wkl[4][4];
#pragma unroll
  for (int mt = 0; mt < 4; ++mt) {
#pragma unroll
    for (int kt = 0; kt < 4; ++kt) {
      f4 a = *(const f4*)(Wq + (16 * mt + n) * 64 + 16 * kt + 4 * g);
      f4 b = *(const f4*)(Wk + (16 * mt + n) * 64 + 16 * kt + 4 * g);
      s16x4 ah, al, bh, bl;
#pragma unroll
      for (int j = 0; j < 4; ++j) {
        bf16 h = (bf16)a[j];
        ah[j] = (short)__builtin_bit_cast(unsigned short, h);
        al[j] = (short)bfbits(a[j] - (float)h);
        bf16 h2 = (bf16)b[j];
        bh[j] = (short)__builtin_bit_cast(unsigned short, h2);
        bl[j] = (short)bfbits(b[j] - (float)h2);
      }
      wqh[mt][kt] = ah; wql[mt][kt] = al;
      wkh[mt][kt] = bh; wkl[mt][kt] = bl;
    }
  }

  // XCD-aware swizzle: consecutive logical ids stay on one XCD (grid 1792 = 8*224)
  const int nwg = gridDim.x;
  const int bid = blockIdx.x;
  const int wid = (bid & 7) * (nwg >> 3) + (bid >> 3);

  const float* wvP  = Wv;
  const float* wfcP = Wfc;

#pragma unroll 1
  for (int nb = wid; nb < 32768; nb += nwg) {
    // keep Wv/Wfc loads inside the loop (prevent LICM register blowup)
    asm volatile("" : "+s"(wvP), "+s"(wfcP));

    const int b  = nb >> 12;
    const int hb = (nb >> 6) & 63;
    const int wb = nb & 63;
    const long base = (long)b * 4194304 + (long)lane * 65536 + hb * 1024 + wb * 4;

    // ---- load input block rows (lane = channel c), split-stage to LDS ----
    f4 vq[4], vr[4];
#pragma unroll
    for (int i = 0; i < 4; ++i) {
      vq[i] = *(const f4*)(qx + base + i * 256);
      vr[i] = *(const f4*)(rx + base + i * 256);
    }
#pragma unroll
    for (int i = 0; i < 4; ++i) {
#pragma unroll
      for (int j = 0; j < 4; ++j) {
        sXq[17 * lane + 4 * i + j] = packsplit(vq[i][j]);
        sXr[17 * lane + 4 * i + j] = packsplit(vr[i][j]);
      }
    }

    // ---- extract input B-frags: X[16kt+4g+j][n], hi and lo planes ----
    s16x4 fqh[4], fql[4], frh[4], frl[4];
#pragma unroll
    for (int kt = 0; kt < 4; ++kt) {
#pragma unroll
      for (int j = 0; j < 4; ++j) {
        uint32_t w  = sXq[17 * (16 * kt + 4 * g + j) + n];
        fqh[kt][j] = (short)(w & 0xffffu);
        fql[kt][j] = (short)(w >> 16);
        uint32_t w2 = sXr[17 * (16 * kt + 4 * g + j) + n];
        frh[kt][j] = (short)(w2 & 0xffffu);
        frl[kt][j] = (short)(w2 >> 16);
      }
    }

    // ---- q = Wq * qb (split: WhXh + WhXl + WlXh), store q^T hi/lo ----
#pragma unroll
    for (int mt = 0; mt < 4; ++mt) {
      f32x4 acc = {0.f, 0.f, 0.f, 0.f};
#pragma unroll
      for (int kt = 0; kt < 4; ++kt) {
        acc = MFMA(wqh[mt][kt], fqh[kt], acc);
        acc = MFMA(wqh[mt][kt], fql[kt], acc);
        acc = MFMA(wql[mt][kt], fqh[kt], acc);
      }
      s16x4 h4, l4;
#pragma unroll
      for (int r = 0; r < 4; ++r) {
        bf16 h = (bf16)acc[r];
        h4[r] = (short)__builtin_bit_cast(unsigned short, h);
        l4[r] = (short)bfbits(acc[r] - (float)h);
      }
      *(s16x4*)&sQT[n * 132 + 16 * mt + 4 * g]      = h4;
      *(s16x4*)&sQT[n * 132 + 64 + 16 * mt + 4 * g] = l4;
    }

    // ---- k = Wk * rb (split), store k^T hi/lo ----
#pragma unroll
    for (int mt = 0; mt < 4; ++mt) {
      f32x4 acc = {0.f, 0.f, 0.f, 0.f};
#pragma unroll
      for (int kt = 0; kt < 4; ++kt) {
        acc = MFMA(wkh[mt][kt], frh[kt], acc);
        acc = MFMA(wkh[mt][kt], frl[kt], acc);
        acc = MFMA(wkl[mt][kt], frh[kt], acc);
      }
      s16x4 h4, l4;
#pragma unroll
      for (int r = 0; r < 4; ++r) {
        bf16 h = (bf16)acc[r];
        h4[r] = (short)__builtin_bit_cast(unsigned short, h);
        l4[r] = (short)bfbits(acc[r] - (float)h);
      }
      *(s16x4*)&sKT[n * 132 + 16 * mt + 4 * g]      = h4;
      *(s16x4*)&sKT[n * 132 + 64 + 16 * mt + 4 * g] = l4;
    }

    // ---- v^T = rb^T * Wv^T : A = rb-frag (same regs as k's B-frag), B = Wv frag
#pragma unroll
    for (int nt = 0; nt < 4; ++nt) {
      f32x4 acc = {0.f, 0.f, 0.f, 0.f};
#pragma unroll
      for (int kt = 0; kt < 4; ++kt) {
        f4 wv = *(const f4*)(wvP + (16 * nt + n) * 64 + 16 * kt + 4 * g);
        s16x4 bw;
#pragma unroll
        for (int j = 0; j < 4; ++j) bw[j] = (short)bfbits(wv[j]);
        acc = MFMA(frh[kt], bw, acc);
      }
      s16x4 h4;
#pragma unroll
      for (int r = 0; r < 4; ++r) h4[r] = (short)bfbits(acc[r]);
      *(s16x4*)&sV[(16 * nt + n) * 20 + 4 * g] = h4;  // v[p][4g..4g+3]
    }

    // ---- energy = q^T k  (3 split pairings) ----
    f32x4 e = {0.f, 0.f, 0.f, 0.f};
#pragma unroll
    for (int kt = 0; kt < 4; ++kt) {
      s16x4 ah = *(const s16x4*)&sQT[n * 132 + 16 * kt + 4 * g];
      s16x4 al = *(const s16x4*)&sQT[n * 132 + 64 + 16 * kt + 4 * g];
      s16x4 bh = *(const s16x4*)&sKT[n * 132 + 16 * kt + 4 * g];
      s16x4 bl = *(const s16x4*)&sKT[n * 132 + 64 + 16 * kt + 4 * g];
      e = MFMA(ah, bh, e);
      e = MFMA(ah, bl, e);
      e = MFMA(al, bh, e);
    }

    // ---- softmax over m (16 lanes of each group hold one row) ----
#pragma unroll
    for (int r = 0; r < 4; ++r) {
      float x = e[r];
      float m = x;
      m = fmaxf(m, __shfl_xor(m, 1));
      m = fmaxf(m, __shfl_xor(m, 2));
      m = fmaxf(m, __shfl_xor(m, 4));
      m = fmaxf(m, __shfl_xor(m, 8));
      float p = __expf(x - m);
      float s = p;
      s += __shfl_xor(s, 1);
      s += __shfl_xor(s, 2);
      s += __shfl_xor(s, 4);
      s += __shfl_xor(s, 8);
      float a = p * __builtin_amdgcn_rcpf(s);
      sP[(4 * g + r) * 20 + n] = bfbits(a);
    }

    // ---- O^T = attn * v^T  (K = 16, one step) ----
    s16x4 ap = *(const s16x4*)&sP[n * 20 + 4 * g];
    f32x4 zero = {0.f, 0.f, 0.f, 0.f};
#pragma unroll
    for (int nt = 0; nt < 4; ++nt) {
      s16x4 bv = *(const s16x4*)&sV[(16 * nt + n) * 20 + 4 * g];
      f32x4 o = MFMA(ap, bv, zero);
      s16x4 h4;
#pragma unroll
      for (int r = 0; r < 4; ++r) h4[r] = (short)bfbits(o[r]);
      *(s16x4*)&sO[(16 * nt + n) * 20 + 4 * g] = h4;  // O[p][4g..4g+3]
    }

    // ---- x = Wfc * O ----
    f32x4 xa[4];
#pragma unroll
    for (int mt = 0; mt < 4; ++mt) xa[mt] = zero;
#pragma unroll
    for (int kt = 0; kt < 4; ++kt) {
      s16x4 fo;
#pragma unroll
      for (int j = 0; j < 4; ++j)
        fo[j] = (short)sO[(16 * kt + 4 * g + j) * 20 + n];
#pragma unroll
      for (int mt = 0; mt < 4; ++mt) {
        f4 wf = *(const f4*)(wfcP + (16 * mt + n) * 64 + 16 * kt + 4 * g);
        s16x4 aw;
#pragma unroll
        for (int j = 0; j < 4; ++j) aw[j] = (short)bfbits(wf[j]);
        xa[mt] = MFMA(aw, fo, xa[mt]);
      }
    }

    // ---- GroupNorm over all 64x16 ----
    float s1 = 0.f, s2 = 0.f;
#pragma unroll
    for (int mt = 0; mt < 4; ++mt) {
#pragma unroll
      for (int r = 0; r < 4; ++r) {
        float v = xa[mt][r];
        s1 += v;
        s2 += v * v;
      }
    }
#pragma unroll
    for (int mask = 1; mask < 64; mask <<= 1) {
      s1 += __shfl_xor(s1, mask);
      s2 += __shfl_xor(s2, mask);
    }
    const float mean = s1 * (1.f / 1024.f);
    const float var  = s2 * (1.f / 1024.f) - mean * mean;
    const float rstd = rsqrtf(var + 1e-5f);

    // ---- affine + residual; write fp32 result back into sXq slots ----
#pragma unroll
    for (int mt = 0; mt < 4; ++mt) {
#pragma unroll
      for (int r = 0; r < 4; ++r) {
        const int row = 16 * mt + 4 * g + r;
        float q0 = unsplit(sXq[17 * row + n]);
        float y = (xa[mt][r] - mean) * rstd * sGn[row] + sGn[64 + row] + q0;
        sXq[17 * row + n] = __builtin_bit_cast(uint32_t, y);
      }
    }

    // ---- transpose-out via LDS, coalesced-ish 16B stores ----
#pragma unroll
    for (int i = 0; i < 4; ++i) {
      f4 o;
#pragma unroll
      for (int j = 0; j < 4; ++j)
        o[j] = __builtin_bit_cast(float, sXq[17 * lane + 4 * i + j]);
      *(f4*)(out + base + i * 256) = o;
    }
  }
}

extern "C" void kernel_launch(void* const* d_in, const int* in_sizes, int n_in,
                              void* d_out, int out_size, void* d_ws, size_t ws_size,
                              hipStream_t stream) {
  const float* qx  = (const float*)d_in[0];
  const float* rx  = (const float*)d_in[1];
  const float* Wq  = (const float*)d_in[2];
  const float* Wk  = (const float*)d_in[3];
  const float* Wv  = (const float*)d_in[4];
  const float* Wfc = (const float*)d_in[5];
  const float* gw  = (const float*)d_in[6];
  const float* gb  = (const float*)d_in[7];
  float* out = (float*)d_out;

  // 1792 = 7 WGs/CU * 256 CUs (LDS-limited residency), multiple of 8 for swizzle
  cvbt_kernel<<<dim3(1792), dim3(64), 0, stream>>>(qx, rx, Wq, Wk, Wv, Wfc, gw, gb, out);
}